// Round 2
// baseline (354.579 us; speedup 1.0000x reference)
//
#include <hip/hip_runtime.h>

typedef unsigned short u16;
typedef __bf16 bf16x8 __attribute__((ext_vector_type(8)));
typedef float f32x4 __attribute__((ext_vector_type(4)));

__device__ __forceinline__ u16 f2bf(float f) {
    union { float f; unsigned u; } v; v.f = f;
    unsigned u = v.u;
    unsigned r = (u + 0x7FFFu + ((u >> 16) & 1u)) >> 16;
    return (u16)r;
}

__device__ __forceinline__ void gload_lds16(const u16* g, u16* l) {
    __builtin_amdgcn_global_load_lds(
        (const __attribute__((address_space(1))) void*)g,
        (__attribute__((address_space(3))) void*)l,
        16, 0, 0);
}

#define BM 128
#define BN 128
#define BK 32

// C = A(MxK,bf16) * BT(NxK,bf16)^T + bias, optional relu, bf16 out.
__global__ __launch_bounds__(256) void gemm_bt(
    const u16* __restrict__ A, const u16* __restrict__ BT,
    const float* __restrict__ bias, u16* __restrict__ C,
    int M, int N, int K, int relu)
{
    __shared__ u16 As[BM * BK];
    __shared__ u16 Bs[BN * BK];
    const int t = threadIdx.x;
    const int lane = t & 63;
    const int wave = t >> 6;
    const int wr = (wave >> 1) * 64;
    const int wc = (wave & 1) * 64;
    const long brow = (long)blockIdx.y * BM;
    const long bcol = (long)blockIdx.x * BN;

    const int r0 = t >> 2;
    const int c0 = (t & 3) * 8;
    const u16* gA0 = A + (brow + r0) * (long)K + c0;
    const u16* gA1 = gA0 + 64L * K;
    const u16* gB0 = BT + (bcol + r0) * (long)K + c0;
    const u16* gB1 = gB0 + 64L * K;

    f32x4 acc[4][4] = {};
    const int fr  = lane & 15;
    const int fko = (lane >> 4) * 8;

    for (int k0 = 0; k0 < K; k0 += BK) {
        gload_lds16(gA0 + k0, &As[t * 8]);
        gload_lds16(gA1 + k0, &As[2048 + t * 8]);
        gload_lds16(gB0 + k0, &Bs[t * 8]);
        gload_lds16(gB1 + k0, &Bs[2048 + t * 8]);
        __syncthreads();

        bf16x8 af[4], bfr[4];
#pragma unroll
        for (int m = 0; m < 4; ++m)
            af[m] = *(const bf16x8*)&As[(wr + m * 16 + fr) * BK + fko];
#pragma unroll
        for (int n = 0; n < 4; ++n)
            bfr[n] = *(const bf16x8*)&Bs[(wc + n * 16 + fr) * BK + fko];
#pragma unroll
        for (int m = 0; m < 4; ++m)
#pragma unroll
            for (int n = 0; n < 4; ++n)
                acc[m][n] = __builtin_amdgcn_mfma_f32_16x16x32_bf16(
                    af[m], bfr[n], acc[m][n], 0, 0, 0);
        __syncthreads();
    }

#pragma unroll
    for (int n = 0; n < 4; ++n) {
        const long col = bcol + wc + n * 16 + fr;
        const float bv = bias[col];
#pragma unroll
        for (int m = 0; m < 4; ++m) {
            const long row = brow + wr + m * 16 + (lane >> 4) * 4;
#pragma unroll
            for (int j = 0; j < 4; ++j) {
                float v = acc[m][n][j] + bv;
                if (relu) v = fmaxf(v, 0.f);
                C[(row + j) * (long)N + col] = f2bf(v);
            }
        }
    }
}

// ---- fused GEMM3 (128x192 tile, groups of 24 cols) + RQS spline ----
#define FBM 128
#define FBN 192
#define FBK 32
#define CLS 200   // padded LDS row stride (u16) for the C tile

__global__ __launch_bounds__(256) void gemm3_rqs(
    const u16* __restrict__ A,       // h2: B x 512 bf16
    const u16* __restrict__ BT,      // W2T padded: 1536 x 512 bf16
    const float* __restrict__ bias,  // b2p: 1536
    const float* __restrict__ x,     // B x 64 fp32
    float* __restrict__ z,           // B x 64 fp32
    float* __restrict__ ldp,         // B x 64 fp32 partial logdet
    int K)
{
    __shared__ u16 smem[FBM * CLS];          // 51200 B; staging aliases the front
    u16* As = smem;                          // 128*32 = 4096 u16
    u16* Bs = smem + FBM * FBK;              // 192*32 = 6144 u16

    const int t = threadIdx.x;
    const int lane = t & 63;
    const int wave = t >> 6;
    const int wr = (wave >> 1) * 64;
    const int wc = (wave & 1) * 96;
    const long brow = (long)blockIdx.y * FBM;
    const int bcol = blockIdx.x * FBN;

    const int r0 = t >> 2;
    const int c0 = (t & 3) * 8;
    const u16* gA0 = A + (brow + r0) * (long)K + c0;
    const u16* gB0 = BT + (long)(bcol + r0) * K + c0;

    f32x4 acc[4][6] = {};
    const int fr  = lane & 15;
    const int fko = (lane >> 4) * 8;

    for (int k0 = 0; k0 < K; k0 += FBK) {
        gload_lds16(gA0 + k0,            &As[t * 8]);
        gload_lds16(gA0 + 64L * K + k0,  &As[2048 + t * 8]);
        gload_lds16(gB0 + k0,            &Bs[t * 8]);
        gload_lds16(gB0 + 64L * K + k0,  &Bs[2048 + t * 8]);
        gload_lds16(gB0 + 128L * K + k0, &Bs[4096 + t * 8]);
        __syncthreads();

        bf16x8 af[4], bfr[6];
#pragma unroll
        for (int m = 0; m < 4; ++m)
            af[m] = *(const bf16x8*)&As[(wr + m * 16 + fr) * FBK + fko];
#pragma unroll
        for (int n = 0; n < 6; ++n)
            bfr[n] = *(const bf16x8*)&Bs[(wc + n * 16 + fr) * FBK + fko];
#pragma unroll
        for (int m = 0; m < 4; ++m)
#pragma unroll
            for (int n = 0; n < 6; ++n)
                acc[m][n] = __builtin_amdgcn_mfma_f32_16x16x32_bf16(
                    af[m], bfr[n], acc[m][n], 0, 0, 0);
        __syncthreads();
    }

    // C tile -> LDS as bf16 (+bias), padded rows
#pragma unroll
    for (int n = 0; n < 6; ++n) {
        const int cl = wc + n * 16 + fr;
        const float bv = bias[bcol + cl];
#pragma unroll
        for (int m = 0; m < 4; ++m) {
            const int rl = wr + m * 16 + (lane >> 4) * 4;
#pragma unroll
            for (int j = 0; j < 4; ++j)
                smem[(rl + j) * CLS + cl] = f2bf(acc[m][n][j] + bv);
        }
    }
    __syncthreads();

    // RQS: 128 rows x 8 dims = 1024 (b,d) pairs; 4 per thread
    const int dbase = bcol / 24;   // = blockIdx.x * 8
#pragma unroll
    for (int pi = 0; pi < 4; ++pi) {
        const int p  = t + pi * 256;
        const int bl = p >> 3;
        const int dl = p & 7;
        const u16* pp = &smem[bl * CLS + dl * 24];
        bf16x8 v0 = *(const bf16x8*)(pp);
        bf16x8 v1 = *(const bf16x8*)(pp + 8);
        bf16x8 v2 = *(const bf16x8*)(pp + 16);

        float w[8], h[8], der[9];
#pragma unroll
        for (int i = 0; i < 8; ++i) w[i] = (float)v0[i];
#pragma unroll
        for (int i = 0; i < 8; ++i) h[i] = (float)v1[i];

        float mw = w[0];
#pragma unroll
        for (int i = 1; i < 8; ++i) mw = fmaxf(mw, w[i]);
        float sw = 0.f;
#pragma unroll
        for (int i = 0; i < 8; ++i) { w[i] = __expf(w[i] - mw); sw += w[i]; }
        float rw = 0.992f / sw;
#pragma unroll
        for (int i = 0; i < 8; ++i) w[i] = 0.001f + w[i] * rw;

        float mh = h[0];
#pragma unroll
        for (int i = 1; i < 8; ++i) mh = fmaxf(mh, h[i]);
        float sh = 0.f;
#pragma unroll
        for (int i = 0; i < 8; ++i) { h[i] = __expf(h[i] - mh); sh += h[i]; }
        float rh = 0.992f / sh;
#pragma unroll
        for (int i = 0; i < 8; ++i) h[i] = 0.001f + h[i] * rh;

        der[0] = 1.f; der[8] = 1.f;
#pragma unroll
        for (int i = 0; i < 7; ++i) {
            float v = (float)v2[i];
            float sp = (v > 20.f) ? v : log1pf(__expf(v));
            der[i + 1] = sp + 0.001f;
        }

        const long b = brow + bl;
        const int  d = dbase + dl;
        float xin = x[b * 64 + d];
        xin = fminf(fmaxf(xin, 0.f), 1.f);

        float x_k = 0.f, y_k = 0.f, w_k = w[0], h_k = h[0], d_k = der[0], d_k1 = der[1];
        float cw = 0.f, ch = 0.f;
#pragma unroll
        for (int i = 1; i < 8; ++i) {
            cw += w[i - 1]; ch += h[i - 1];
            if (cw < xin) { x_k = cw; y_k = ch; w_k = w[i]; h_k = h[i]; d_k = der[i]; d_k1 = der[i + 1]; }
        }

        float s   = h_k / w_k;
        float th  = (xin - x_k) / w_k;
        float t1t = th * (1.f - th);
        float den = s + (d_k + d_k1 - 2.f * s) * t1t;
        float out = y_k + h_k * (s * th * th + d_k * t1t) / (den + 1e-6f);
        float om  = 1.f - th;
        float nom = s * s * (d_k1 * th * th + 2.f * s * t1t + d_k * om * om);
        float logdet = __logf(nom / (den * den + 1e-6f));

        z[b * 64 + d]   = out;
        ldp[b * 64 + d] = logdet;
    }
}

__global__ __launch_bounds__(256) void ld_reduce(
    const float* __restrict__ ldp, float* __restrict__ ld)
{
    const int b = blockIdx.x * 4 + (threadIdx.x >> 6);
    const int lane = threadIdx.x & 63;
    float r = ldp[(long)b * 64 + lane];
#pragma unroll
    for (int off = 32; off; off >>= 1) r += __shfl_xor(r, off, 64);
    if (lane == 0) ld[b] = r;
}

__global__ void cvt_x_bf16(const float* __restrict__ in, u16* __restrict__ out, long n) {
    long i = (long)blockIdx.x * blockDim.x + threadIdx.x;
    long stride = (long)gridDim.x * blockDim.x;
    for (; i < n; i += stride) out[i] = f2bf(in[i]);
}

__global__ void transpose_w_bf16(const float* __restrict__ W, u16* __restrict__ WT,
                                 int K, int N) {
    long total = (long)N * K;
    long i = (long)blockIdx.x * blockDim.x + threadIdx.x;
    long stride = (long)gridDim.x * blockDim.x;
    for (; i < total; i += stride) {
        int n = (int)(i / K), k = (int)(i % K);
        WT[i] = f2bf(W[(long)k * N + n]);
    }
}

__global__ void transpose_w2_bf16(const float* __restrict__ W, u16* __restrict__ WT, int K) {
    long total = 1536L * K;
    long i = (long)blockIdx.x * blockDim.x + threadIdx.x;
    long stride = (long)gridDim.x * blockDim.x;
    for (; i < total; i += stride) {
        int npad = (int)(i / K), k = (int)(i % K);
        int g = npad / 24, r = npad % 24;
        float v = (r < 23) ? W[(long)k * 1472 + g * 23 + r] : 0.f;
        WT[i] = f2bf(v);
    }
}

__global__ void pad_bias2(const float* __restrict__ b2, float* __restrict__ b2p) {
    int c = blockIdx.x * 256 + threadIdx.x;
    if (c < 1536) {
        int g = c / 24, r = c % 24;
        b2p[c] = (r < 23) ? b2[g * 23 + r] : 0.f;
    }
}

// diagnostic: if workspace is too small, make the failure unambiguous (error ~2.0)
__global__ void fill_fail(float* __restrict__ out, long n) {
    long i = (long)blockIdx.x * blockDim.x + threadIdx.x;
    long stride = (long)gridDim.x * blockDim.x;
    for (; i < n; i += stride) out[i] = -1.0f;
}

extern "C" void kernel_launch(void* const* d_in, const int* in_sizes, int n_in,
                              void* d_out, int out_size, void* d_ws, size_t ws_size,
                              hipStream_t stream)
{
    const float* x  = (const float*)d_in[0];
    const float* W0 = (const float*)d_in[1];
    const float* b0 = (const float*)d_in[2];
    const float* W1 = (const float*)d_in[3];
    const float* b1 = (const float*)d_in[4];
    const float* W2 = (const float*)d_in[5];
    const float* b2 = (const float*)d_in[6];
    const int B = in_sizes[0] / 64;   // 65536
    const int D = 64, H = 512, NP = 1536;

    char* ws = (char*)d_ws;
    size_t off = 0;
    u16* W0T = (u16*)(ws + off); off += (size_t)H * D * 2;      // 64 KB
    u16* W1T = (u16*)(ws + off); off += (size_t)H * H * 2;      // 512 KB
    u16* W2T = (u16*)(ws + off); off += (size_t)NP * H * 2;     // 1.5 MB
    float* b2p = (float*)(ws + off); off += (size_t)NP * 4;     // 6 KB
    off = (off + 255) & ~(size_t)255;
    // regionA: h1 during GEMM1/2, then ldp (f32 B*64) during fused+reduce
    u16*   h1  = (u16*)(ws + off);
    float* ldp = (float*)(ws + off);
    off += (size_t)B * H * 2;                                   // 64 MB
    // regionB: xb during GEMM1 (dead after), then h2
    u16* xb = (u16*)(ws + off);
    u16* h2 = (u16*)(ws + off);
    off += (size_t)B * H * 2;                                   // 64 MB
    size_t need = off;

    float* zout  = (float*)d_out;
    float* ldout = zout + (size_t)B * D;

    if (ws_size < need) {
        fill_fail<<<2048, 256, 0, stream>>>(zout, (long)out_size);
        return;
    }

    cvt_x_bf16<<<2048, 256, 0, stream>>>(x, xb, (long)B * D);
    transpose_w_bf16<<<128, 256, 0, stream>>>(W0, W0T, D, H);
    transpose_w_bf16<<<1024, 256, 0, stream>>>(W1, W1T, H, H);
    transpose_w2_bf16<<<3072, 256, 0, stream>>>(W2, W2T, H);
    pad_bias2<<<6, 256, 0, stream>>>(b2, b2p);

    dim3 g12(H / BN, B / BM);          // (4, 512)
    gemm_bt<<<g12, 256, 0, stream>>>(xb, W0T, b0, h1, B, H, D, 1);
    // GEMM2 writes h2 over xb region; xb is dead, h1 is in regionA
    gemm_bt<<<g12, 256, 0, stream>>>(h1, W1T, b1, h2, B, H, H, 1);

    dim3 g3(NP / FBN, B / FBM);        // (8, 512)
    gemm3_rqs<<<g3, 256, 0, stream>>>(h2, W2T, b2p, x, zout, ldp, H);

    ld_reduce<<<B / 4, 256, 0, stream>>>(ldp, ldout);
}

// Round 3
// 285.032 us; speedup vs baseline: 1.2440x; 1.2440x over previous
//
#include <hip/hip_runtime.h>

typedef unsigned short u16;
typedef __bf16 bf16x8 __attribute__((ext_vector_type(8)));
typedef float f32x4 __attribute__((ext_vector_type(4)));

// cheap float->bf16: round via +0x8000 then truncate (<=1ulp vs RNE), 2 VALU ops
__device__ __forceinline__ u16 f2bf_r(float f) {
    union { float f; unsigned u; } v; v.f = f;
    return (u16)((v.u + 0x8000u) >> 16);
}
__device__ __forceinline__ float rcpf(float x) { return __builtin_amdgcn_rcpf(x); }

__device__ __forceinline__ void gload_lds16(const u16* g, u16* l) {
    __builtin_amdgcn_global_load_lds(
        (const __attribute__((address_space(1))) void*)g,
        (__attribute__((address_space(3))) void*)l,
        16, 0, 0);
}

#define BM 128
#define BN 128
#define BK 32

// C = A(MxK,bf16) * BT(NxK,bf16)^T + bias, optional relu, bf16 out.
__global__ __launch_bounds__(256) void gemm_bt(
    const u16* __restrict__ A, const u16* __restrict__ BT,
    const float* __restrict__ bias, u16* __restrict__ C,
    int M, int N, int K, int relu)
{
    __shared__ u16 As[BM * BK];
    __shared__ u16 Bs[BN * BK];
    const int t = threadIdx.x;
    const int lane = t & 63;
    const int wave = t >> 6;
    const int wr = (wave >> 1) * 64;
    const int wc = (wave & 1) * 64;
    const long brow = (long)blockIdx.y * BM;
    const long bcol = (long)blockIdx.x * BN;

    const int r0 = t >> 2;
    const int c0 = (t & 3) * 8;
    const u16* gA0 = A + (brow + r0) * (long)K + c0;
    const u16* gA1 = gA0 + 64L * K;
    const u16* gB0 = BT + (bcol + r0) * (long)K + c0;
    const u16* gB1 = gB0 + 64L * K;

    f32x4 acc[4][4] = {};
    const int fr  = lane & 15;
    const int fko = (lane >> 4) * 8;

    for (int k0 = 0; k0 < K; k0 += BK) {
        gload_lds16(gA0 + k0, &As[t * 8]);
        gload_lds16(gA1 + k0, &As[2048 + t * 8]);
        gload_lds16(gB0 + k0, &Bs[t * 8]);
        gload_lds16(gB1 + k0, &Bs[2048 + t * 8]);
        __syncthreads();

        bf16x8 af[4], bfr[4];
#pragma unroll
        for (int m = 0; m < 4; ++m)
            af[m] = *(const bf16x8*)&As[(wr + m * 16 + fr) * BK + fko];
#pragma unroll
        for (int n = 0; n < 4; ++n)
            bfr[n] = *(const bf16x8*)&Bs[(wc + n * 16 + fr) * BK + fko];
#pragma unroll
        for (int m = 0; m < 4; ++m)
#pragma unroll
            for (int n = 0; n < 4; ++n)
                acc[m][n] = __builtin_amdgcn_mfma_f32_16x16x32_bf16(
                    af[m], bfr[n], acc[m][n], 0, 0, 0);
        __syncthreads();
    }

#pragma unroll
    for (int n = 0; n < 4; ++n) {
        const long col = bcol + wc + n * 16 + fr;
        const float bv = bias[col];
#pragma unroll
        for (int m = 0; m < 4; ++m) {
            const long row = brow + wr + m * 16 + (lane >> 4) * 4;
#pragma unroll
            for (int j = 0; j < 4; ++j) {
                float v = acc[m][n][j] + bv;
                if (relu) v = fmaxf(v, 0.f);
                C[(row + j) * (long)N + col] = f2bf_r(v);
            }
        }
    }
}

// ---- fused GEMM3 (64x192 tile) + RQS spline ----
// 64x192 C-tile => 25.6 KB LDS => 6 blocks/CU so VALU-phase blocks overlap
// MFMA-phase blocks (separate pipes, m114).
#define FBM 64
#define FBN 192
#define FBK 32
#define CLS 200   // padded LDS row stride (u16) for the C tile

__global__ __launch_bounds__(256) void gemm3_rqs(
    const u16* __restrict__ A,       // h2: B x 512 bf16
    const u16* __restrict__ BT,      // W2T padded: 1536 x 512 bf16
    const float* __restrict__ bias,  // b2p: 1536
    const float* __restrict__ x,     // B x 64 fp32
    float* __restrict__ z,           // B x 64 fp32
    float* __restrict__ ldp,         // B x 64 fp32 partial logdet
    int K)
{
    __shared__ u16 smem[FBM * CLS];          // 25600 B; staging aliases the front
    u16* As = smem;                          // 64*32  = 2048 u16 (4 KB)
    u16* Bs = smem + FBM * FBK;              // 192*32 = 6144 u16 (12 KB)

    const int t = threadIdx.x;
    const int lane = t & 63;
    const int wave = t >> 6;
    const int wc = wave * 48;                // 4 waves x 48 cols
    const long brow = (long)blockIdx.y * FBM;
    const int bcol = blockIdx.x * FBN;

    const int r0 = t >> 2;
    const int c0 = (t & 3) * 8;
    const u16* gA0 = A + (brow + r0) * (long)K + c0;
    const u16* gB0 = BT + (long)(bcol + r0) * K + c0;

    f32x4 acc[4][3] = {};
    const int fr  = lane & 15;
    const int fko = (lane >> 4) * 8;

    for (int k0 = 0; k0 < K; k0 += FBK) {
        gload_lds16(gA0 + k0,            &As[t * 8]);
        gload_lds16(gB0 + k0,            &Bs[t * 8]);
        gload_lds16(gB0 + 64L * K + k0,  &Bs[2048 + t * 8]);
        gload_lds16(gB0 + 128L * K + k0, &Bs[4096 + t * 8]);
        __syncthreads();

        bf16x8 af[4], bfr[3];
#pragma unroll
        for (int m = 0; m < 4; ++m)
            af[m] = *(const bf16x8*)&As[(m * 16 + fr) * FBK + fko];
#pragma unroll
        for (int n = 0; n < 3; ++n)
            bfr[n] = *(const bf16x8*)&Bs[(wc + n * 16 + fr) * FBK + fko];
#pragma unroll
        for (int m = 0; m < 4; ++m)
#pragma unroll
            for (int n = 0; n < 3; ++n)
                acc[m][n] = __builtin_amdgcn_mfma_f32_16x16x32_bf16(
                    af[m], bfr[n], acc[m][n], 0, 0, 0);
        __syncthreads();
    }

    // C tile -> LDS as bf16 (+bias), padded rows
#pragma unroll
    for (int n = 0; n < 3; ++n) {
        const int cl = wc + n * 16 + fr;
        const float bv = bias[bcol + cl];
#pragma unroll
        for (int m = 0; m < 4; ++m) {
            const int rl = m * 16 + (lane >> 4) * 4;
#pragma unroll
            for (int j = 0; j < 4; ++j)
                smem[(rl + j) * CLS + cl] = f2bf_r(acc[m][n][j] + bv);
        }
    }
    __syncthreads();

    // RQS: 64 rows x 8 dims = 512 (b,d) pairs; 2 per thread
    const int dbase = blockIdx.x * 8;
#pragma unroll
    for (int pi = 0; pi < 2; ++pi) {
        const int p  = t + pi * 256;
        const int bl = p >> 3;
        const int dl = p & 7;
        const u16* pp = &smem[bl * CLS + dl * 24];
        bf16x8 v0 = *(const bf16x8*)(pp);        // widths
        bf16x8 v1 = *(const bf16x8*)(pp + 8);    // heights
        bf16x8 v2 = *(const bf16x8*)(pp + 16);   // raw derivs (7) + pad(=0)

        // softmax WITHOUT max-subtraction (|params| ~ O(1), exp can't overflow)
        float w[8], h[8];
        float sw = 0.f, sh = 0.f;
#pragma unroll
        for (int i = 0; i < 8; ++i) { w[i] = __expf((float)v0[i]); sw += w[i]; }
#pragma unroll
        for (int i = 0; i < 8; ++i) { h[i] = __expf((float)v1[i]); sh += h[i]; }
        const float rw = 0.992f * rcpf(sw);
        const float rh = 0.992f * rcpf(sh);
#pragma unroll
        for (int i = 0; i < 8; ++i) w[i] = fmaf(w[i], rw, 0.001f);
#pragma unroll
        for (int i = 0; i < 8; ++i) h[i] = fmaf(h[i], rh, 0.001f);

        const long b = brow + bl;
        const int  d = dbase + dl;
        float xin = x[b * 64 + d];
        xin = fminf(fmaxf(xin, 0.f), 1.f);

        // bin select; pick RAW deriv params, softplus only the 2 selected
        float x_k = 0.f, y_k = 0.f, w_k = w[0], h_k = h[0];
        float rk = 0.f, rk1 = (float)v2[0];
        bool isfirst = true, islast = false;
        float cw = 0.f, ch = 0.f;
#pragma unroll
        for (int i = 1; i < 8; ++i) {
            cw += w[i - 1]; ch += h[i - 1];
            if (cw < xin) {
                x_k = cw; y_k = ch; w_k = w[i]; h_k = h[i];
                rk = (float)v2[i - 1];
                rk1 = (i < 7) ? (float)v2[i] : 0.f;
                isfirst = false; islast = (i == 7);
            }
        }
        // cheap softplus: log(1+e^v) via native exp/log
        float sp_k  = __logf(1.f + __expf(rk));
        float sp_k1 = __logf(1.f + __expf(rk1));
        float d_k  = isfirst ? 1.f : sp_k  + 0.001f;
        float d_k1 = islast  ? 1.f : sp_k1 + 0.001f;

        const float inv_wk = rcpf(w_k);
        const float s   = h_k * inv_wk;
        const float th  = (xin - x_k) * inv_wk;
        const float omt = 1.f - th;
        const float t1t = th * omt;
        const float den = fmaf(d_k + d_k1 - 2.f * s, t1t, s);
        const float num = fmaf(s * th, th, d_k * t1t);
        const float out = fmaf(h_k * num, rcpf(den + 1e-6f), y_k);
        const float nom = s * s * fmaf(d_k1 * th, th, fmaf(2.f * s, t1t, d_k * omt * omt));
        const float logdet = __logf(nom) - __logf(fmaf(den, den, 1e-6f));

        z[b * 64 + d]   = out;
        ldp[b * 64 + d] = logdet;
    }
}

__global__ __launch_bounds__(256) void ld_reduce(
    const float* __restrict__ ldp, float* __restrict__ ld)
{
    const int b = blockIdx.x * 4 + (threadIdx.x >> 6);
    const int lane = threadIdx.x & 63;
    float r = ldp[(long)b * 64 + lane];
#pragma unroll
    for (int off = 32; off; off >>= 1) r += __shfl_xor(r, off, 64);
    if (lane == 0) ld[b] = r;
}

__global__ void cvt_x_bf16(const float* __restrict__ in, u16* __restrict__ out, long n) {
    long i = (long)blockIdx.x * blockDim.x + threadIdx.x;
    long stride = (long)gridDim.x * blockDim.x;
    for (; i < n; i += stride) out[i] = f2bf_r(in[i]);
}

__global__ void transpose_w_bf16(const float* __restrict__ W, u16* __restrict__ WT,
                                 int K, int N) {
    long total = (long)N * K;
    long i = (long)blockIdx.x * blockDim.x + threadIdx.x;
    long stride = (long)gridDim.x * blockDim.x;
    for (; i < total; i += stride) {
        int n = (int)(i / K), k = (int)(i % K);
        WT[i] = f2bf_r(W[(long)k * N + n]);
    }
}

__global__ void transpose_w2_bf16(const float* __restrict__ W, u16* __restrict__ WT, int K) {
    long total = 1536L * K;
    long i = (long)blockIdx.x * blockDim.x + threadIdx.x;
    long stride = (long)gridDim.x * blockDim.x;
    for (; i < total; i += stride) {
        int npad = (int)(i / K), k = (int)(i % K);
        int g = npad / 24, r = npad % 24;
        float v = (r < 23) ? W[(long)k * 1472 + g * 23 + r] : 0.f;
        WT[i] = f2bf_r(v);
    }
}

__global__ void pad_bias2(const float* __restrict__ b2, float* __restrict__ b2p) {
    int c = blockIdx.x * 256 + threadIdx.x;
    if (c < 1536) {
        int g = c / 24, r = c % 24;
        b2p[c] = (r < 23) ? b2[g * 23 + r] : 0.f;
    }
}

__global__ void fill_fail(float* __restrict__ out, long n) {
    long i = (long)blockIdx.x * blockDim.x + threadIdx.x;
    long stride = (long)gridDim.x * blockDim.x;
    for (; i < n; i += stride) out[i] = -1.0f;
}

extern "C" void kernel_launch(void* const* d_in, const int* in_sizes, int n_in,
                              void* d_out, int out_size, void* d_ws, size_t ws_size,
                              hipStream_t stream)
{
    const float* x  = (const float*)d_in[0];
    const float* W0 = (const float*)d_in[1];
    const float* b0 = (const float*)d_in[2];
    const float* W1 = (const float*)d_in[3];
    const float* b1 = (const float*)d_in[4];
    const float* W2 = (const float*)d_in[5];
    const float* b2 = (const float*)d_in[6];
    const int B = in_sizes[0] / 64;   // 65536
    const int D = 64, H = 512, NP = 1536;

    char* ws = (char*)d_ws;
    size_t off = 0;
    u16* W0T = (u16*)(ws + off); off += (size_t)H * D * 2;
    u16* W1T = (u16*)(ws + off); off += (size_t)H * H * 2;
    u16* W2T = (u16*)(ws + off); off += (size_t)NP * H * 2;
    float* b2p = (float*)(ws + off); off += (size_t)NP * 4;
    off = (off + 255) & ~(size_t)255;
    // regionA: h1 during GEMM1/2, then ldp (f32 B*64) during fused+reduce
    u16*   h1  = (u16*)(ws + off);
    float* ldp = (float*)(ws + off);
    off += (size_t)B * H * 2;
    // regionB: xb during GEMM1 (dead after), then h2
    u16* xb = (u16*)(ws + off);
    u16* h2 = (u16*)(ws + off);
    off += (size_t)B * H * 2;
    size_t need = off;

    float* zout  = (float*)d_out;
    float* ldout = zout + (size_t)B * D;

    if (ws_size < need) {
        fill_fail<<<2048, 256, 0, stream>>>(zout, (long)out_size);
        return;
    }

    cvt_x_bf16<<<2048, 256, 0, stream>>>(x, xb, (long)B * D);
    transpose_w_bf16<<<128, 256, 0, stream>>>(W0, W0T, D, H);
    transpose_w_bf16<<<1024, 256, 0, stream>>>(W1, W1T, H, H);
    transpose_w2_bf16<<<3072, 256, 0, stream>>>(W2, W2T, H);
    pad_bias2<<<6, 256, 0, stream>>>(b2, b2p);

    dim3 g12(H / BN, B / BM);          // (4, 512)
    gemm_bt<<<g12, 256, 0, stream>>>(xb, W0T, b0, h1, B, H, D, 1);
    gemm_bt<<<g12, 256, 0, stream>>>(h1, W1T, b1, h2, B, H, H, 1);

    dim3 g3(NP / FBN, B / FBM);        // (8, 1024)
    gemm3_rqs<<<g3, 256, 0, stream>>>(h2, W2T, b2p, x, zout, ldp, H);

    ld_reduce<<<B / 4, 256, 0, stream>>>(ldp, ldout);
}